// Round 15
// baseline (158.695 us; speedup 1.0000x reference)
//
#include <hip/hip_runtime.h>
#include <stdint.h>

#define HEADS 12
#define DH 64
#define SEQ 1024
#define BATCH 2
#define DIMC 768
#define MROWS (BATCH*SEQ)   // 2048
#define NQKV (3*DIMC)       // 2304

typedef __bf16 bf16x8 __attribute__((ext_vector_type(8)));
typedef float f32x4 __attribute__((ext_vector_type(4)));
typedef unsigned int u32x4 __attribute__((ext_vector_type(4)));

__device__ __forceinline__ uint16_t f2bf(float f) {
  uint32_t u = __builtin_bit_cast(uint32_t, f);
  uint32_t r = (u + 0x7fffu + ((u >> 16) & 1u)) >> 16;
  return (uint16_t)r;
}

// raw hardware 2^x (v_exp_f32) -- no ocml range-fixup overhead
__device__ __forceinline__ float fexp2(float x) {
  float r;
  asm("v_exp_f32 %0, %1" : "=v"(r) : "v"(x));
  return r;
}

// async global -> LDS, 16 B per lane (wave writes base + lane*16)
__device__ __forceinline__ void gl16(const void* g, void* l) {
  __builtin_amdgcn_global_load_lds(
      (const __attribute__((address_space(1))) void*)g,
      (__attribute__((address_space(3))) void*)l, 16, 0, 0);
}

// ---------------- prep (fused): cast x to bf16 + all four weight transposes ----------------
__global__ __launch_bounds__(256) void k_prep(
    const float* __restrict__ x1, const float* __restrict__ x2,
    const float* __restrict__ Wqkv1, const float* __restrict__ Wqkv2,
    const float* __restrict__ Wp1, const float* __restrict__ Wp2,
    uint16_t* __restrict__ xb,
    uint16_t* __restrict__ wqkvt, uint16_t* __restrict__ wpt) {
  const int tid = threadIdx.x;
  if (blockIdx.x < 3072) {
    int i = blockIdx.x * 256 + tid;           // float4 index
    const int per = MROWS * DIMC / 4;         // 393216 per stream
    const float* src = (i < per) ? x1 : x2;
    int j = (i < per) ? i : (i - per);
    float4 v = reinterpret_cast<const float4*>(src)[j];
    reinterpret_cast<ushort4*>(xb)[i] =
        make_ushort4(f2bf(v.x), f2bf(v.y), f2bf(v.z), f2bf(v.w));
    return;
  }
  __shared__ uint16_t tile[32][33];
  int id = blockIdx.x - 3072;
  const float* src; uint16_t* dst; int C, xo, yo;
  if (id < 3456) {                 // 2 x (72*24) tiles for Wqkv
    int s = id / 1728; id %= 1728;
    src = s ? Wqkv2 : Wqkv1; dst = wqkvt + (size_t)s * NQKV * DIMC; C = NQKV;
    xo = id % 72; yo = id / 72;
  } else {                         // 2 x (24*24) tiles for Wp
    id -= 3456; int s = id / 576; id %= 576;
    src = s ? Wp2 : Wp1; dst = wpt + (size_t)s * DIMC * DIMC; C = DIMC;
    xo = id % 24; yo = id / 24;
  }
  const int R = DIMC;
  int c0 = xo * 32, r0 = yo * 32;
  int tx = tid & 31, ty = tid >> 5;
  for (int rr = ty; rr < 32; rr += 8)
    tile[rr][tx] = f2bf(src[(size_t)(r0 + rr) * C + c0 + tx]);
  __syncthreads();
  for (int rr = ty; rr < 32; rr += 8)
    dst[(size_t)(c0 + rr) * R + r0 + tx] = tile[tx][rr];
}

// ---------------- QKV GEMM v5: single bf16 pass, 128x64 tile, BK=64 ----------------
__global__ __launch_bounds__(256) void k_qkv_gemm(
    const uint16_t* __restrict__ xb,
    const uint16_t* __restrict__ wt,   // [2][2304][768] (W transposed)
    uint16_t* __restrict__ qo, uint16_t* __restrict__ ko, uint16_t* __restrict__ vto) {
  __shared__ __align__(16) uint16_t Ax[2][128][64];
  __shared__ __align__(16) uint16_t Bt[2][64][64];

  int flat = blockIdx.x + 16 * blockIdx.y + 576 * blockIdx.z;   // 1152 blocks
  flat = (flat & 7) * 144 + (flat >> 3);
  const int yb = flat % 36;
  const int xbk = (flat / 36) % 16;
  const int s  = flat / 576;
  const int m0 = xbk * 128;
  const int col0 = yb * 64;

  const uint16_t* x_s  = xb + (size_t)s * MROWS * DIMC;
  const uint16_t* wt_s = wt + (size_t)s * NQKV * DIMC;

  const int tid = threadIdx.x;
  const int w = tid >> 6, lane = tid & 63;
  const int lr = lane & 15, g = lane >> 4;
  const int srow8 = lane >> 3;                    // 0..7
  const int schunk8 = ((lane & 7) ^ srow8) * 8;   // pre-swizzled source chunk

  f32x4 acc[2][4] = {};

  size_t aoff[4], boff[2];
#pragma unroll
  for (int j = 0; j < 4; ++j)
    aoff[j] = (size_t)(m0 + w * 32 + j * 8 + srow8) * DIMC + schunk8;
#pragma unroll
  for (int j = 0; j < 2; ++j)
    boff[j] = (size_t)(col0 + w * 16 + j * 8 + srow8) * DIMC + schunk8;

#define STAGE(B, K0) do {                                  \
    gl16(x_s  + aoff[0] + (K0), &Ax[B][w * 32 +  0][0]);   \
    gl16(x_s  + aoff[1] + (K0), &Ax[B][w * 32 +  8][0]);   \
    gl16(x_s  + aoff[2] + (K0), &Ax[B][w * 32 + 16][0]);   \
    gl16(x_s  + aoff[3] + (K0), &Ax[B][w * 32 + 24][0]);   \
    gl16(wt_s + boff[0] + (K0), &Bt[B][w * 16 +  0][0]);   \
    gl16(wt_s + boff[1] + (K0), &Bt[B][w * 16 +  8][0]); } while (0)

  STAGE(0, 0);                       // 6 loads in flight

  for (int kt = 0; kt < 12; ++kt) {
    const int cur = kt & 1;
    if (kt < 11) {
      STAGE(cur ^ 1, (kt + 1) * 64);
      asm volatile("s_waitcnt vmcnt(6)" ::: "memory");
    } else {
      asm volatile("s_waitcnt vmcnt(0)" ::: "memory");
    }
    __builtin_amdgcn_s_barrier();
    __builtin_amdgcn_sched_barrier(0);

    bf16x8 ah[2][2], bb[4][2];
#pragma unroll
    for (int fm = 0; fm < 2; ++fm)
#pragma unroll
      for (int kk = 0; kk < 2; ++kk) {
        const int ch = ((kk * 4 + g) ^ (lr & 7)) * 8;
        ah[fm][kk] = *reinterpret_cast<const bf16x8*>(&Ax[cur][w * 32 + fm * 16 + lr][ch]);
      }
#pragma unroll
    for (int fn = 0; fn < 4; ++fn)
#pragma unroll
      for (int kk = 0; kk < 2; ++kk) {
        const int ch = ((kk * 4 + g) ^ (lr & 7)) * 8;
        bb[fn][kk] = *reinterpret_cast<const bf16x8*>(&Bt[cur][fn * 16 + lr][ch]);
      }

    asm volatile("s_waitcnt lgkmcnt(0)" ::: "memory");
    __builtin_amdgcn_sched_barrier(0);
    __builtin_amdgcn_s_setprio(1);
#pragma unroll
    for (int fm = 0; fm < 2; ++fm)
#pragma unroll
      for (int fn = 0; fn < 4; ++fn)
#pragma unroll
        for (int kk = 0; kk < 2; ++kk)
          acc[fm][fn] = __builtin_amdgcn_mfma_f32_16x16x32_bf16(ah[fm][kk], bb[fn][kk], acc[fm][fn], 0, 0, 0);
    __builtin_amdgcn_s_setprio(0);
    __builtin_amdgcn_sched_barrier(0);
    __builtin_amdgcn_s_barrier();
  }
#undef STAGE

  const int t = col0 / 768;
  const int cbase = col0 % 768;
  const int h = cbase >> 6;
  uint16_t* q_s  = qo  + (size_t)s * 1572864;
  uint16_t* k_s  = ko  + (size_t)s * 1572864;
  uint16_t* vt_s = vto + (size_t)s * 1572864;
#pragma unroll
  for (int fm = 0; fm < 2; ++fm)
#pragma unroll
    for (int fn = 0; fn < 4; ++fn) {
      const int dh = fn * 16 + lr;
#pragma unroll
      for (int i = 0; i < 4; ++i) {
        int m = m0 + w * 32 + fm * 16 + g * 4 + i;
        int b_ = m >> 10, n = m & 1023;
        float v = acc[fm][fn][i];
        if (t == 0)
          q_s[((size_t)(b_ * HEADS + h) * SEQ + n) * DH + dh] = f2bf(v * 0.125f);
        else if (t == 1)
          k_s[((size_t)(b_ * HEADS + h) * SEQ + n) * DH + dh] = f2bf(v);
        else
          vt_s[((size_t)(b_ * HEADS + h) * DH + dh) * SEQ + n] = f2bf(v);
      }
    }
}

// ---------------- fused dual-pass flash attention v10 ----------------
// r11 structure exactly (256 thr, 16 q-rows/wave, 2-phase dbuf, fixed-max
// v_exp softmax) EXCEPT: V is NOT staged in LDS. V tiles are read straight
// from L2 into registers (8 x 16B per tile per wave; 16-row x 64B pattern,
// fully-consumed cache lines; issued at phase start so QK+softmax covers
// the ~200cy L2 latency). LDS traffic halves; LDS size 32->16 KB.
#define SWKEY(r) ((((r) >> 2) ^ (r)) & 7)
#define MFMA16 __builtin_amdgcn_mfma_f32_16x16x32_bf16

__global__ __launch_bounds__(256) void k_attn(
    const uint16_t* __restrict__ q, const uint16_t* __restrict__ k,
    const uint16_t* __restrict__ vt, uint16_t* __restrict__ o) {
  __shared__ uint16_t Klds[2][64][64];   // [key][dh], chunk c holds global chunk c^SWKEY(row)

  int bid = blockIdx.x;
  bid = (bid & 7) * 96 + (bid >> 3);
  const int qt = bid & 15;
  int rest = bid >> 4;            // 0..47
  const int h = rest % 12;
  int rest2 = rest / 12;          // 0..3
  const int b = rest2 & 1;
  const int s = rest2 >> 1;

  const int tid = threadIdx.x;
  const int w = tid >> 6, lane = tid & 63;
  const int lr = lane & 15;
  const int g = lane >> 4;        // 0..3
  const int hi8 = g * 8;

  const uint16_t* q_s = q + (size_t)s * 1572864 +
                        ((size_t)(b * HEADS + h) * SEQ + qt * 64 + w * 16 + lr) * DH;
  const bf16x8 qf0 = *reinterpret_cast<const bf16x8*>(&q_s[hi8]);
  const bf16x8 qf1 = *reinterpret_cast<const bf16x8*>(&q_s[32 + hi8]);

  const int klo = (lr >> 2) * 8 + (lr & 3);

  const int r0 = tid >> 3;                    // 0..31 (and r0+32; same SWKEY)
  const int c0 = tid & 7;
  const int swck = 8 * (c0 ^ SWKEY(r0));

  const uint16_t* kbase0 = k  + (size_t)s * 1572864 + (size_t)(b * HEADS + h) * SEQ * DH;
  const uint16_t* vbase0 = vt + (size_t)s * 1572864 + (size_t)(b * HEADS + h) * DH * SEQ;
  const uint16_t* kbase1 = k  + (size_t)(1 - s) * 1572864 + (size_t)(b * HEADS + h) * SEQ * DH;
  const uint16_t* vbase1 = vt + (size_t)(1 - s) * 1572864 + (size_t)(b * HEADS + h) * DH * SEQ;

  // per-lane V row offsets (row = fn*16 + lr), chunks g and 4+g
  size_t vroff[4];
#pragma unroll
  for (int fn = 0; fn < 4; ++fn)
    vroff[fn] = (size_t)(fn * 16 + lr) * SEQ + g * 8;

  u32x4 kr0, kr1;
  bf16x8 vv[8];

#define LOADK(T) { const int tt = (T); const int kt_ = tt & 15;                             \
    const uint16_t* kp = (tt >= 16) ? kbase1 : kbase0;                                      \
    kr0 = *reinterpret_cast<const u32x4*>(&kp[(size_t)(kt_ * 64 + r0) * DH + c0 * 8]);      \
    kr1 = *reinterpret_cast<const u32x4*>(&kp[(size_t)(kt_ * 64 + r0 + 32) * DH + c0 * 8]); }

#define STOREK(B) {                                               \
    *reinterpret_cast<u32x4*>(&Klds[B][r0][swck]) = kr0;          \
    *reinterpret_cast<u32x4*>(&Klds[B][r0 + 32][swck]) = kr1; }

  // V for tile T straight from global/L2 into regs
#define LOADV(T) { const int tt = (T); const int kt_ = tt & 15;                             \
    const uint16_t* vp = (tt >= 16) ? vbase1 : vbase0;                                      \
    _Pragma("unroll")                                                                       \
    for (int fn = 0; fn < 4; ++fn) {                                                        \
      vv[2 * fn]     = *reinterpret_cast<const bf16x8*>(&vp[vroff[fn] + kt_ * 64]);         \
      vv[2 * fn + 1] = *reinterpret_cast<const bf16x8*>(&vp[vroff[fn] + kt_ * 64 + 32]);    \
    } }

  f32x4 Oacc[4] = {};
  f32x4 Ofin[4] = {};
  float lrow = 0.f;

#define COMPUTE(BUF)                                                              \
  {                                                                               \
    f32x4 S[4];                                                                   \
    __builtin_amdgcn_s_setprio(1);                                                \
    _Pragma("unroll")                                                             \
    for (int fn = 0; fn < 4; ++fn) {                                              \
      const int krow = klo + 4 * (fn & 1) + 32 * (fn >> 1);                       \
      const int sw = SWKEY(krow);                                                 \
      bf16x8 ka = *reinterpret_cast<const bf16x8*>(&Klds[BUF][krow][8 * (g ^ sw)]);        \
      bf16x8 kb = *reinterpret_cast<const bf16x8*>(&Klds[BUF][krow][8 * ((4 + g) ^ sw)]);  \
      f32x4 z = {};                                                               \
      z = MFMA16(ka, qf0, z, 0, 0, 0);                                            \
      S[fn] = MFMA16(kb, qf1, z, 0, 0, 0);                                        \
    }                                                                             \
    __builtin_amdgcn_s_setprio(0);                                                \
    float rs0 = 0.f, rs1 = 0.f, rs2 = 0.f, rs3 = 0.f;                             \
    _Pragma("unroll")                                                             \
    for (int i = 0; i < 4; ++i) {                                                 \
      float p0 = fexp2(fmaf(S[0][i], 1.442695041f, -17.31234049f));               \
      float p1 = fexp2(fmaf(S[1][i], 1.442695041f, -17.31234049f));               \
      float p2 = fexp2(fmaf(S[2][i], 1.442695041f, -17.31234049f));               \
      float p3 = fexp2(fmaf(S[3][i], 1.442695041f, -17.31234049f));               \
      S[0][i] = p0; S[1][i] = p1; S[2][i] = p2; S[3][i] = p3;                     \
      rs0 += p0; rs1 += p1; rs2 += p2; rs3 += p3;                                 \
    }                                                                             \
    lrow += (rs0 + rs1) + (rs2 + rs3);                                            \
    bf16x8 pa0, pa1;                                                              \
    _Pragma("unroll")                                                             \
    for (int i = 0; i < 4; ++i) {                                                 \
      pa0[i] = (__bf16)S[0][i]; pa0[4 + i] = (__bf16)S[1][i];                     \
      pa1[i] = (__bf16)S[2][i]; pa1[4 + i] = (__bf16)S[3][i];                     \
    }                                                                             \
    __builtin_amdgcn_s_setprio(1);                                                \
    _Pragma("unroll")                                                             \
    for (int fn = 0; fn < 4; ++fn) {                                              \
      Oacc[fn] = MFMA16(pa0, vv[2 * fn], Oacc[fn], 0, 0, 0);                      \
      Oacc[fn] = MFMA16(pa1, vv[2 * fn + 1], Oacc[fn], 0, 0, 0);                  \
    }                                                                             \
    __builtin_amdgcn_s_setprio(0);                                                \
  }

#define PASS_EPI(RESET)                                                           \
  {                                                                               \
    float lsum = lrow + __shfl_xor(lrow, 16);                                     \
    lsum += __shfl_xor(lsum, 32);                                                 \
    const float linv = 1.f / lsum;                                                \
    float li0 = __shfl(linv, 20 * g + 0), li1 = __shfl(linv, 20 * g + 1);         \
    float li2 = __shfl(linv, 20 * g + 2), li3 = __shfl(linv, 20 * g + 3);         \
    _Pragma("unroll")                                                             \
    for (int fn = 0; fn < 4; ++fn) {                                              \
      Ofin[fn][0] += Oacc[fn][0] * li0; Ofin[fn][1] += Oacc[fn][1] * li1;         \
      Ofin[fn][2] += Oacc[fn][2] * li2; Ofin[fn][3] += Oacc[fn][3] * li3;         \
    }                                                                             \
    if (RESET) {                                                                  \
      lrow = 0.f;                                                                 \
      _Pragma("unroll") for (int fn = 0; fn < 4; ++fn) Oacc[fn] = f32x4{};        \
    }                                                                             \
  }

  // prologue: buf0 = K tile0
  LOADK(0);
  STOREK(0);
  __syncthreads();

#pragma unroll 1
  for (int t2 = 0; t2 < 16; ++t2) {
    // half A: tile 2t2 from buf0; stage K(2t2+1) -> buf1
    LOADV(2 * t2);            // V in flight during QK+softmax
    LOADK(2 * t2 + 1);
    COMPUTE(0);
    STOREK(1);
    __syncthreads();
    // half B: tile 2t2+1 from buf1; stage K(2t2+2) -> buf0
    LOADV(2 * t2 + 1);
    if (t2 < 15) LOADK(2 * t2 + 2);
    COMPUTE(1);
    if (t2 == 7)  PASS_EPI(1);
    if (t2 == 15) PASS_EPI(0);
    if (t2 < 15) STOREK(0);
    __syncthreads();
  }
#undef LOADK
#undef STOREK
#undef LOADV
#undef COMPUTE
#undef PASS_EPI

  uint16_t* o_s = o + (size_t)s * MROWS * DIMC;
#pragma unroll
  for (int fn = 0; fn < 4; ++fn)
#pragma unroll
    for (int i = 0; i < 4; ++i) {
      int n = qt * 64 + w * 16 + g * 4 + i;
      int col = h * 64 + fn * 16 + lr;
      o_s[(size_t)(b * SEQ + n) * DIMC + col] = f2bf(Ofin[fn][i]);
    }
}

// ---------------- projection GEMM v4: counted-vmcnt 2-barrier pipeline ----------------
__global__ __launch_bounds__(256) void k_proj_gemm(
    const uint16_t* __restrict__ o, const uint16_t* __restrict__ wpt,
    const float* __restrict__ bp1, const float* __restrict__ bp2,
    float* __restrict__ out) {
  __shared__ __align__(16) uint16_t At[2][128][32];
  __shared__ __align__(16) uint16_t Bt[2][64][32];

  int flat = blockIdx.x + 16 * blockIdx.y + 192 * blockIdx.z;   // 384 blocks
  flat = (flat & 7) * 48 + (flat >> 3);
  const int yb = flat % 12;
  const int xb = (flat / 12) % 16;
  const int s  = flat / 192;
  const int m0 = xb * 128;
  const int col0 = yb * 64;

  const uint16_t* o_s = o + (size_t)s * MROWS * DIMC;
  const uint16_t* w_s = wpt + (size_t)s * DIMC * DIMC;
  const float* bias = (s == 0) ? bp1 : bp2;
  float* out_s = out + (size_t)s * MROWS * DIMC;

  const int tid = threadIdx.x;
  const int w = tid >> 6, lane = tid & 63;
  const int lr = lane & 15, g = lane >> 4;
  const int pc = (g ^ ((lr >> 1) & 3)) * 8;
  const int srow = lane >> 2;
  const int schunk = ((lane & 3) ^ ((lane >> 3) & 3)) * 8;

  f32x4 acc[2][4] = {};

  const size_t aoff0 = (size_t)(m0 + w * 32 + srow) * DIMC + schunk;
  const size_t aoff1 = (size_t)(m0 + w * 32 + 16 + srow) * DIMC + schunk;
  const size_t boff  = (size_t)(col0 + w * 16 + srow) * DIMC + schunk;

#define STAGE(B, K0) do {                                      \
    gl16(o_s + aoff0 + (K0), &At[B][w * 32][0]);               \
    gl16(o_s + aoff1 + (K0), &At[B][w * 32 + 16][0]);          \
    gl16(w_s + boff  + (K0), &Bt[B][w * 16][0]); } while (0)

  STAGE(0, 0);

  for (int kt = 0; kt < 24; ++kt) {
    const int cur = kt & 1;
    if (kt < 23) {
      STAGE(cur ^ 1, (kt + 1) * 32);
      asm volatile("s_waitcnt vmcnt(3)" ::: "memory");
    } else {
      asm volatile("s_waitcnt vmcnt(0)" ::: "memory");
    }
    __builtin_amdgcn_s_barrier();
    __builtin_amdgcn_sched_barrier(0);

    bf16x8 a[2], bb[4];
#pragma unroll
    for (int f = 0; f < 2; ++f)
      a[f] = *reinterpret_cast<const bf16x8*>(&At[cur][w * 32 + f * 16 + lr][pc]);
#pragma unroll
    for (int f = 0; f < 4; ++f)
      bb[f] = *reinterpret_cast<const bf16x8*>(&Bt[cur][f * 16 + lr][pc]);

    asm volatile("s_waitcnt lgkmcnt(0)" ::: "memory");
    __builtin_amdgcn_sched_barrier(0);
    __builtin_amdgcn_s_setprio(1);
#pragma unroll
    for (int fm = 0; fm < 2; ++fm)
#pragma unroll
      for (int fn = 0; fn < 4; ++fn)
        acc[fm][fn] = __builtin_amdgcn_mfma_f32_16x16x32_bf16(a[fm], bb[fn], acc[fm][fn], 0, 0, 0);
    __builtin_amdgcn_s_setprio(0);
    __builtin_amdgcn_sched_barrier(0);
    __builtin_amdgcn_s_barrier();
  }
#undef STAGE

#pragma unroll
  for (int fm = 0; fm < 2; ++fm)
#pragma unroll
    for (int fn = 0; fn < 4; ++fn) {
      const int col = col0 + fn * 16 + lr;
      const float bv = bias[col];
#pragma unroll
      for (int i = 0; i < 4; ++i) {
        int m = m0 + w * 32 + fm * 16 + g * 4 + i;
        out_s[(size_t)m * DIMC + col] = acc[fm][fn][i] + bv;
      }
    }
}

extern "C" void kernel_launch(void* const* d_in, const int* in_sizes, int n_in,
                              void* d_out, int out_size, void* d_ws, size_t ws_size,
                              hipStream_t stream) {
  const float* x1    = (const float*)d_in[0];
  const float* x2    = (const float*)d_in[1];
  const float* Wqkv1 = (const float*)d_in[2];
  const float* Wqkv2 = (const float*)d_in[3];
  const float* Wp1   = (const float*)d_in[4];
  const float* bp1   = (const float*)d_in[5];
  const float* Wp2   = (const float*)d_in[6];
  const float* bp2   = (const float*)d_in[7];
  float* out = (float*)d_out;

  uint8_t* ws = (uint8_t*)d_ws;
  uint16_t* xbuf  = (uint16_t*)(ws);             // 2*2048*768 bf16 = 6291456 B
  uint16_t* wqkvt = (uint16_t*)(ws + 12582912);  // 2*2304*768 = 7077888 B
  uint16_t* wpt   = (uint16_t*)(ws + 19660800);  // 2*768*768  = 2359296 B
  uint16_t* qb    = (uint16_t*)(ws + 22020096);  // 2*1572864  = 6291456 B
  uint16_t* kb    = (uint16_t*)(ws + 28311552);
  uint16_t* vtb   = (uint16_t*)(ws + 34603008);
  uint16_t* ob    = (uint16_t*)(ws + 40894464);  // total 47185920 B

  k_prep<<<7680, 256, 0, stream>>>(x1, x2, Wqkv1, Wqkv2, Wp1, Wp2, xbuf, wqkvt, wpt);
  k_qkv_gemm<<<dim3(16, 36, 2), 256, 0, stream>>>(xbuf, wqkvt, qb, kb, vtb);
  k_attn<<<768, 256, 0, stream>>>(qb, kb, vtb, ob);
  k_proj_gemm<<<dim3(16, 12, 2), 256, 0, stream>>>(ob, wpt, bp1, bp2, out);
}

// Round 16
// 104.924 us; speedup vs baseline: 1.5125x; 1.5125x over previous
//
#include <hip/hip_runtime.h>
#include <stdint.h>

#define HEADS 12
#define DH 64
#define SEQ 1024
#define BATCH 2
#define DIMC 768
#define MROWS (BATCH*SEQ)   // 2048
#define NQKV (3*DIMC)       // 2304

typedef __bf16 bf16x8 __attribute__((ext_vector_type(8)));
typedef float f32x4 __attribute__((ext_vector_type(4)));
typedef unsigned int u32x4 __attribute__((ext_vector_type(4)));

__device__ __forceinline__ uint16_t f2bf(float f) {
  uint32_t u = __builtin_bit_cast(uint32_t, f);
  uint32_t r = (u + 0x7fffu + ((u >> 16) & 1u)) >> 16;
  return (uint16_t)r;
}

// raw hardware 2^x (v_exp_f32) -- no ocml range-fixup overhead
__device__ __forceinline__ float fexp2(float x) {
  float r;
  asm("v_exp_f32 %0, %1" : "=v"(r) : "v"(x));
  return r;
}

// async global -> LDS, 16 B per lane (wave writes base + lane*16)
__device__ __forceinline__ void gl16(const void* g, void* l) {
  __builtin_amdgcn_global_load_lds(
      (const __attribute__((address_space(1))) void*)g,
      (__attribute__((address_space(3))) void*)l, 16, 0, 0);
}

// ---------------- prep (fused): cast x to bf16 + all four weight transposes ----------------
__global__ __launch_bounds__(256) void k_prep(
    const float* __restrict__ x1, const float* __restrict__ x2,
    const float* __restrict__ Wqkv1, const float* __restrict__ Wqkv2,
    const float* __restrict__ Wp1, const float* __restrict__ Wp2,
    uint16_t* __restrict__ xb,
    uint16_t* __restrict__ wqkvt, uint16_t* __restrict__ wpt) {
  const int tid = threadIdx.x;
  if (blockIdx.x < 3072) {
    int i = blockIdx.x * 256 + tid;           // float4 index
    const int per = MROWS * DIMC / 4;         // 393216 per stream
    const float* src = (i < per) ? x1 : x2;
    int j = (i < per) ? i : (i - per);
    float4 v = reinterpret_cast<const float4*>(src)[j];
    reinterpret_cast<ushort4*>(xb)[i] =
        make_ushort4(f2bf(v.x), f2bf(v.y), f2bf(v.z), f2bf(v.w));
    return;
  }
  __shared__ uint16_t tile[32][33];
  int id = blockIdx.x - 3072;
  const float* src; uint16_t* dst; int C, xo, yo;
  if (id < 3456) {                 // 2 x (72*24) tiles for Wqkv
    int s = id / 1728; id %= 1728;
    src = s ? Wqkv2 : Wqkv1; dst = wqkvt + (size_t)s * NQKV * DIMC; C = NQKV;
    xo = id % 72; yo = id / 72;
  } else {                         // 2 x (24*24) tiles for Wp
    id -= 3456; int s = id / 576; id %= 576;
    src = s ? Wp2 : Wp1; dst = wpt + (size_t)s * DIMC * DIMC; C = DIMC;
    xo = id % 24; yo = id / 24;
  }
  const int R = DIMC;
  int c0 = xo * 32, r0 = yo * 32;
  int tx = tid & 31, ty = tid >> 5;
  for (int rr = ty; rr < 32; rr += 8)
    tile[rr][tx] = f2bf(src[(size_t)(r0 + rr) * C + c0 + tx]);
  __syncthreads();
  for (int rr = ty; rr < 32; rr += 8)
    dst[(size_t)(c0 + rr) * R + r0 + tx] = tile[tx][rr];
}

// ---------------- QKV GEMM v6: 128x128 tile, BK=32, counted-vmcnt dbuf ----------------
// LDS chunk-swizzle (r4-validated, 0 conflicts): stored chunk p of row r holds
// global chunk p ^ ((r>>1)&3); write via pre-swizzled global source (linear
// gl16 dest, rule #21), read at pc = (g ^ ((lr>>1)&3))*8.
__global__ __launch_bounds__(256) void k_qkv_gemm(
    const uint16_t* __restrict__ xb,
    const uint16_t* __restrict__ wt,   // [2][2304][768] (W transposed)
    uint16_t* __restrict__ qo, uint16_t* __restrict__ ko, uint16_t* __restrict__ vto) {
  __shared__ __align__(16) uint16_t Ax[2][128][32];
  __shared__ __align__(16) uint16_t Bt[2][128][32];

  int flat = blockIdx.x + 16 * blockIdx.y + 288 * blockIdx.z;   // 576 blocks
  flat = (flat & 7) * 72 + (flat >> 3);                         // bijective (576%8==0)
  const int yb = flat % 18;
  const int xbk = (flat / 18) % 16;
  const int s  = flat / 288;
  const int m0 = xbk * 128;
  const int col0 = yb * 128;

  const uint16_t* x_s  = xb + (size_t)s * MROWS * DIMC;
  const uint16_t* wt_s = wt + (size_t)s * NQKV * DIMC;

  const int tid = threadIdx.x;
  const int w = tid >> 6, lane = tid & 63;
  const int wm = w >> 1, wn = w & 1;
  const int lr = lane & 15, g = lane >> 4;
  const int pc = (g ^ ((lr >> 1) & 3)) * 8;                   // swizzled frag chunk
  const int srow = lane >> 2;                                 // 0..15
  const int schunk = ((lane & 3) ^ ((lane >> 3) & 3)) * 8;    // pre-swizzled source chunk

  f32x4 acc[4][4] = {};

  const size_t aoff0 = (size_t)(m0 + w * 32 + srow) * DIMC + schunk;
  const size_t aoff1 = (size_t)(m0 + w * 32 + 16 + srow) * DIMC + schunk;
  const size_t boff0 = (size_t)(col0 + w * 32 + srow) * DIMC + schunk;
  const size_t boff1 = (size_t)(col0 + w * 32 + 16 + srow) * DIMC + schunk;

#define STAGE(B, K0) do {                                   \
    gl16(x_s  + aoff0 + (K0), &Ax[B][w * 32][0]);           \
    gl16(x_s  + aoff1 + (K0), &Ax[B][w * 32 + 16][0]);      \
    gl16(wt_s + boff0 + (K0), &Bt[B][w * 32][0]);           \
    gl16(wt_s + boff1 + (K0), &Bt[B][w * 32 + 16][0]); } while (0)

  STAGE(0, 0);                       // 4 loads in flight

  for (int kt = 0; kt < 24; ++kt) {
    const int cur = kt & 1;
    if (kt < 23) {
      STAGE(cur ^ 1, (kt + 1) * 32);                    // outstanding: 8
      asm volatile("s_waitcnt vmcnt(4)" ::: "memory");  // cur's 4 done, next's 4 in flight
    } else {
      asm volatile("s_waitcnt vmcnt(0)" ::: "memory");
    }
    __builtin_amdgcn_s_barrier();
    __builtin_amdgcn_sched_barrier(0);

    bf16x8 a[4], bb[4];
#pragma unroll
    for (int f = 0; f < 4; ++f) {
      a[f]  = *reinterpret_cast<const bf16x8*>(&Ax[cur][wm * 64 + f * 16 + lr][pc]);
      bb[f] = *reinterpret_cast<const bf16x8*>(&Bt[cur][wn * 64 + f * 16 + lr][pc]);
    }

    asm volatile("s_waitcnt lgkmcnt(0)" ::: "memory");
    __builtin_amdgcn_sched_barrier(0);
    __builtin_amdgcn_s_setprio(1);
#pragma unroll
    for (int fm = 0; fm < 4; ++fm)
#pragma unroll
      for (int fn = 0; fn < 4; ++fn)
        acc[fm][fn] = __builtin_amdgcn_mfma_f32_16x16x32_bf16(a[fm], bb[fn], acc[fm][fn], 0, 0, 0);
    __builtin_amdgcn_s_setprio(0);
    __builtin_amdgcn_sched_barrier(0);
    __builtin_amdgcn_s_barrier();
  }
#undef STAGE

  const int t = col0 / 768;       // 128 | 768: tiles never straddle q/k/v
  const int cbase = col0 % 768;
  uint16_t* q_s  = qo  + (size_t)s * 1572864;
  uint16_t* k_s  = ko  + (size_t)s * 1572864;
  uint16_t* vt_s = vto + (size_t)s * 1572864;
#pragma unroll
  for (int fm = 0; fm < 4; ++fm)
#pragma unroll
    for (int fn = 0; fn < 4; ++fn) {
      const int col_in = cbase + wn * 64 + fn * 16 + lr;
      const int h = col_in >> 6, dh = col_in & 63;
#pragma unroll
      for (int i = 0; i < 4; ++i) {
        int m = m0 + wm * 64 + fm * 16 + g * 4 + i;
        int b_ = m >> 10, n = m & 1023;
        float v = acc[fm][fn][i];
        if (t == 0)
          q_s[((size_t)(b_ * HEADS + h) * SEQ + n) * DH + dh] = f2bf(v * 0.125f);
        else if (t == 1)
          k_s[((size_t)(b_ * HEADS + h) * SEQ + n) * DH + dh] = f2bf(v);
        else
          vt_s[((size_t)(b_ * HEADS + h) * DH + dh) * SEQ + n] = f2bf(v);
      }
    }
}

// ---------------- fused dual-pass flash attention v6 (r11, frozen) ----------------
#define SWKEY(r) ((((r) >> 2) ^ (r)) & 7)
#define MFMA16 __builtin_amdgcn_mfma_f32_16x16x32_bf16

__global__ __launch_bounds__(256) void k_attn(
    const uint16_t* __restrict__ q, const uint16_t* __restrict__ k,
    const uint16_t* __restrict__ vt, uint16_t* __restrict__ o) {
  __shared__ uint16_t Klds[2][64][64];   // [key][dh], chunk c holds global chunk c^SWKEY(row)
  __shared__ uint16_t Vlds[2][64][64];   // [dh][key], same swizzle

  int bid = blockIdx.x;
  bid = (bid & 7) * 96 + (bid >> 3);
  const int qt = bid & 15;
  int rest = bid >> 4;            // 0..47
  const int h = rest % 12;
  int rest2 = rest / 12;          // 0..3
  const int b = rest2 & 1;
  const int s = rest2 >> 1;

  const int tid = threadIdx.x;
  const int w = tid >> 6, lane = tid & 63;
  const int lr = lane & 15;
  const int g = lane >> 4;        // 0..3
  const int hi8 = g * 8;

  const uint16_t* q_s = q + (size_t)s * 1572864 +
                        ((size_t)(b * HEADS + h) * SEQ + qt * 64 + w * 16 + lr) * DH;
  const bf16x8 qf0 = *reinterpret_cast<const bf16x8*>(&q_s[hi8]);
  const bf16x8 qf1 = *reinterpret_cast<const bf16x8*>(&q_s[32 + hi8]);

  const int klo = (lr >> 2) * 8 + (lr & 3);

  const int r0 = tid >> 3;                    // 0..31 (and r0+32; same SWKEY)
  const int c0 = tid & 7;
  const int swck = 8 * (c0 ^ SWKEY(r0));

  const uint16_t* kbase0 = k  + (size_t)s * 1572864 + (size_t)(b * HEADS + h) * SEQ * DH;
  const uint16_t* vbase0 = vt + (size_t)s * 1572864 + (size_t)(b * HEADS + h) * DH * SEQ;
  const uint16_t* kbase1 = k  + (size_t)(1 - s) * 1572864 + (size_t)(b * HEADS + h) * SEQ * DH;
  const uint16_t* vbase1 = vt + (size_t)(1 - s) * 1572864 + (size_t)(b * HEADS + h) * DH * SEQ;

  u32x4 kr0, kr1, vr0, vr1;

#define LOADT(T) { const int tt = (T); const int kt_ = tt & 15;                             \
    const uint16_t* kp = (tt >= 16) ? kbase1 : kbase0;                                      \
    const uint16_t* vp = (tt >= 16) ? vbase1 : vbase0;                                      \
    kr0 = *reinterpret_cast<const u32x4*>(&kp[(size_t)(kt_ * 64 + r0) * DH + c0 * 8]);      \
    kr1 = *reinterpret_cast<const u32x4*>(&kp[(size_t)(kt_ * 64 + r0 + 32) * DH + c0 * 8]); \
    vr0 = *reinterpret_cast<const u32x4*>(&vp[(size_t)r0 * SEQ + kt_ * 64 + c0 * 8]);       \
    vr1 = *reinterpret_cast<const u32x4*>(&vp[(size_t)(r0 + 32) * SEQ + kt_ * 64 + c0 * 8]); }

#define STORET(B) {                                               \
    *reinterpret_cast<u32x4*>(&Klds[B][r0][swck]) = kr0;          \
    *reinterpret_cast<u32x4*>(&Klds[B][r0 + 32][swck]) = kr1;     \
    *reinterpret_cast<u32x4*>(&Vlds[B][r0][swck]) = vr0;          \
    *reinterpret_cast<u32x4*>(&Vlds[B][r0 + 32][swck]) = vr1; }

  LOADT(0);
  STORET(0);
  __syncthreads();

  f32x4 Oacc[4] = {};
  f32x4 Ofin[4] = {};
  float lrow = 0.f;

#define COMPUTE(CUR)                                                              \
  {                                                                               \
    f32x4 S[4];                                                                   \
    __builtin_amdgcn_s_setprio(1);                                                \
    _Pragma("unroll")                                                             \
    for (int fn = 0; fn < 4; ++fn) {                                              \
      const int krow = klo + 4 * (fn & 1) + 32 * (fn >> 1);                       \
      const int sw = SWKEY(krow);                                                 \
      bf16x8 ka = *reinterpret_cast<const bf16x8*>(&Klds[CUR][krow][8 * (g ^ sw)]);        \
      bf16x8 kb = *reinterpret_cast<const bf16x8*>(&Klds[CUR][krow][8 * ((4 + g) ^ sw)]);  \
      f32x4 z = {};                                                               \
      z = MFMA16(ka, qf0, z, 0, 0, 0);                                            \
      S[fn] = MFMA16(kb, qf1, z, 0, 0, 0);                                        \
    }                                                                             \
    __builtin_amdgcn_s_setprio(0);                                                \
    float rs0 = 0.f, rs1 = 0.f, rs2 = 0.f, rs3 = 0.f;                             \
    _Pragma("unroll")                                                             \
    for (int i = 0; i < 4; ++i) {                                                 \
      float p0 = fexp2(fmaf(S[0][i], 1.442695041f, -17.31234049f));               \
      float p1 = fexp2(fmaf(S[1][i], 1.442695041f, -17.31234049f));               \
      float p2 = fexp2(fmaf(S[2][i], 1.442695041f, -17.31234049f));               \
      float p3 = fexp2(fmaf(S[3][i], 1.442695041f, -17.31234049f));               \
      S[0][i] = p0; S[1][i] = p1; S[2][i] = p2; S[3][i] = p3;                     \
      rs0 += p0; rs1 += p1; rs2 += p2; rs3 += p3;                                 \
    }                                                                             \
    lrow += (rs0 + rs1) + (rs2 + rs3);                                            \
    bf16x8 pa0, pa1;                                                              \
    _Pragma("unroll")                                                             \
    for (int i = 0; i < 4; ++i) {                                                 \
      pa0[i] = (__bf16)S[0][i]; pa0[4 + i] = (__bf16)S[1][i];                     \
      pa1[i] = (__bf16)S[2][i]; pa1[4 + i] = (__bf16)S[3][i];                     \
    }                                                                             \
    __builtin_amdgcn_s_setprio(1);                                                \
    _Pragma("unroll")                                                             \
    for (int fn = 0; fn < 4; ++fn) {                                              \
      const int vrow = fn * 16 + lr;                                              \
      const int sw = SWKEY(vrow);                                                 \
      bf16x8 va = *reinterpret_cast<const bf16x8*>(&Vlds[CUR][vrow][8 * (g ^ sw)]);        \
      bf16x8 vb = *reinterpret_cast<const bf16x8*>(&Vlds[CUR][vrow][8 * ((4 + g) ^ sw)]);  \
      Oacc[fn] = MFMA16(pa0, va, Oacc[fn], 0, 0, 0);                              \
      Oacc[fn] = MFMA16(pa1, vb, Oacc[fn], 0, 0, 0);                              \
    }                                                                             \
    __builtin_amdgcn_s_setprio(0);                                                \
  }

#define PASS_EPI(RESET)                                                           \
  {                                                                               \
    float lsum = lrow + __shfl_xor(lrow, 16);                                     \
    lsum += __shfl_xor(lsum, 32);                                                 \
    const float linv = 1.f / lsum;                                                \
    float li0 = __shfl(linv, 20 * g + 0), li1 = __shfl(linv, 20 * g + 1);         \
    float li2 = __shfl(linv, 20 * g + 2), li3 = __shfl(linv, 20 * g + 3);         \
    _Pragma("unroll")                                                             \
    for (int fn = 0; fn < 4; ++fn) {                                              \
      Ofin[fn][0] += Oacc[fn][0] * li0; Ofin[fn][1] += Oacc[fn][1] * li1;         \
      Ofin[fn][2] += Oacc[fn][2] * li2; Ofin[fn][3] += Oacc[fn][3] * li3;         \
    }                                                                             \
    if (RESET) {                                                                  \
      lrow = 0.f;                                                                 \
      _Pragma("unroll") for (int fn = 0; fn < 4; ++fn) Oacc[fn] = f32x4{};        \
    }                                                                             \
  }

#pragma unroll 1
  for (int t2 = 0; t2 < 16; ++t2) {
    LOADT(2 * t2 + 1);
    COMPUTE(0);
    STORET(1);
    __syncthreads();
    if (t2 < 15) LOADT(2 * t2 + 2);
    COMPUTE(1);
    if (t2 == 7)  PASS_EPI(1);
    if (t2 == 15) PASS_EPI(0);
    if (t2 < 15) STORET(0);
    __syncthreads();
  }
#undef LOADT
#undef STORET
#undef COMPUTE
#undef PASS_EPI

  uint16_t* o_s = o + (size_t)s * MROWS * DIMC;
#pragma unroll
  for (int fn = 0; fn < 4; ++fn)
#pragma unroll
    for (int i = 0; i < 4; ++i) {
      int n = qt * 64 + w * 16 + g * 4 + i;
      int col = h * 64 + fn * 16 + lr;
      o_s[(size_t)(b * SEQ + n) * DIMC + col] = f2bf(Ofin[fn][i]);
    }
}

// ---------------- projection GEMM v4 (r11, frozen) ----------------
__global__ __launch_bounds__(256) void k_proj_gemm(
    const uint16_t* __restrict__ o, const uint16_t* __restrict__ wpt,
    const float* __restrict__ bp1, const float* __restrict__ bp2,
    float* __restrict__ out) {
  __shared__ __align__(16) uint16_t At[2][128][32];
  __shared__ __align__(16) uint16_t Bt[2][64][32];

  int flat = blockIdx.x + 16 * blockIdx.y + 192 * blockIdx.z;   // 384 blocks
  flat = (flat & 7) * 48 + (flat >> 3);
  const int yb = flat % 12;
  const int xb = (flat / 12) % 16;
  const int s  = flat / 192;
  const int m0 = xb * 128;
  const int col0 = yb * 64;

  const uint16_t* o_s = o + (size_t)s * MROWS * DIMC;
  const uint16_t* w_s = wpt + (size_t)s * DIMC * DIMC;
  const float* bias = (s == 0) ? bp1 : bp2;
  float* out_s = out + (size_t)s * MROWS * DIMC;

  const int tid = threadIdx.x;
  const int w = tid >> 6, lane = tid & 63;
  const int lr = lane & 15, g = lane >> 4;
  const int pc = (g ^ ((lr >> 1) & 3)) * 8;
  const int srow = lane >> 2;
  const int schunk = ((lane & 3) ^ ((lane >> 3) & 3)) * 8;

  f32x4 acc[2][4] = {};

  const size_t aoff0 = (size_t)(m0 + w * 32 + srow) * DIMC + schunk;
  const size_t aoff1 = (size_t)(m0 + w * 32 + 16 + srow) * DIMC + schunk;
  const size_t boff  = (size_t)(col0 + w * 16 + srow) * DIMC + schunk;

#define STAGE(B, K0) do {                                      \
    gl16(o_s + aoff0 + (K0), &At[B][w * 32][0]);               \
    gl16(o_s + aoff1 + (K0), &At[B][w * 32 + 16][0]);          \
    gl16(w_s + boff  + (K0), &Bt[B][w * 16][0]); } while (0)

  STAGE(0, 0);

  for (int kt = 0; kt < 24; ++kt) {
    const int cur = kt & 1;
    if (kt < 23) {
      STAGE(cur ^ 1, (kt + 1) * 32);
      asm volatile("s_waitcnt vmcnt(3)" ::: "memory");
    } else {
      asm volatile("s_waitcnt vmcnt(0)" ::: "memory");
    }
    __builtin_amdgcn_s_barrier();
    __builtin_amdgcn_sched_barrier(0);

    bf16x8 a[2], bb[4];
#pragma unroll
    for (int f = 0; f < 2; ++f)
      a[f] = *reinterpret_cast<const bf16x8*>(&At[cur][w * 32 + f * 16 + lr][pc]);
#pragma unroll
    for (int f = 0; f < 4; ++f)
      bb[f] = *reinterpret_cast<const bf16x8*>(&Bt[cur][f * 16 + lr][pc]);

    asm volatile("s_waitcnt lgkmcnt(0)" ::: "memory");
    __builtin_amdgcn_sched_barrier(0);
    __builtin_amdgcn_s_setprio(1);
#pragma unroll
    for (int fm = 0; fm < 2; ++fm)
#pragma unroll
      for (int fn = 0; fn < 4; ++fn)
        acc[fm][fn] = __builtin_amdgcn_mfma_f32_16x16x32_bf16(a[fm], bb[fn], acc[fm][fn], 0, 0, 0);
    __builtin_amdgcn_s_setprio(0);
    __builtin_amdgcn_sched_barrier(0);
    __builtin_amdgcn_s_barrier();
  }
#undef STAGE

#pragma unroll
  for (int fm = 0; fm < 2; ++fm)
#pragma unroll
    for (int fn = 0; fn < 4; ++fn) {
      const int col = col0 + fn * 16 + lr;
      const float bv = bias[col];
#pragma unroll
      for (int i = 0; i < 4; ++i) {
        int m = m0 + w * 32 + fm * 16 + g * 4 + i;
        out_s[(size_t)m * DIMC + col] = acc[fm][fn][i] + bv;
      }
    }
}

extern "C" void kernel_launch(void* const* d_in, const int* in_sizes, int n_in,
                              void* d_out, int out_size, void* d_ws, size_t ws_size,
                              hipStream_t stream) {
  const float* x1    = (const float*)d_in[0];
  const float* x2    = (const float*)d_in[1];
  const float* Wqkv1 = (const float*)d_in[2];
  const float* Wqkv2 = (const float*)d_in[3];
  const float* Wp1   = (const float*)d_in[4];
  const float* bp1   = (const float*)d_in[5];
  const float* Wp2   = (const float*)d_in[6];
  const float* bp2   = (const float*)d_in[7];
  float* out = (float*)d_out;

  uint8_t* ws = (uint8_t*)d_ws;
  uint16_t* xbuf  = (uint16_t*)(ws);             // 2*2048*768 bf16 = 6291456 B
  uint16_t* wqkvt = (uint16_t*)(ws + 12582912);  // 2*2304*768 = 7077888 B
  uint16_t* wpt   = (uint16_t*)(ws + 19660800);  // 2*768*768  = 2359296 B
  uint16_t* qb    = (uint16_t*)(ws + 22020096);  // 2*1572864  = 6291456 B
  uint16_t* kb    = (uint16_t*)(ws + 28311552);
  uint16_t* vtb   = (uint16_t*)(ws + 34603008);
  uint16_t* ob    = (uint16_t*)(ws + 40894464);  // total 47185920 B

  k_prep<<<7680, 256, 0, stream>>>(x1, x2, Wqkv1, Wqkv2, Wp1, Wp2, xbuf, wqkvt, wpt);
  k_qkv_gemm<<<dim3(16, 18, 2), 256, 0, stream>>>(xbuf, wqkvt, qb, kb, vtb);
  k_attn<<<768, 256, 0, stream>>>(qb, kb, vtb, ob);
  k_proj_gemm<<<dim3(16, 12, 2), 256, 0, stream>>>(ob, wpt, bp1, bp2, out);
}

// Round 17
// 102.676 us; speedup vs baseline: 1.5456x; 1.0219x over previous
//
#include <hip/hip_runtime.h>
#include <stdint.h>

#define HEADS 12
#define DH 64
#define SEQ 1024
#define BATCH 2
#define DIMC 768
#define MROWS (BATCH*SEQ)   // 2048
#define NQKV (3*DIMC)       // 2304

typedef __bf16 bf16x8 __attribute__((ext_vector_type(8)));
typedef float f32x4 __attribute__((ext_vector_type(4)));
typedef unsigned int u32x4 __attribute__((ext_vector_type(4)));

__device__ __forceinline__ uint16_t f2bf(float f) {
  uint32_t u = __builtin_bit_cast(uint32_t, f);
  uint32_t r = (u + 0x7fffu + ((u >> 16) & 1u)) >> 16;
  return (uint16_t)r;
}

// raw hardware 2^x (v_exp_f32) -- no ocml range-fixup overhead
__device__ __forceinline__ float fexp2(float x) {
  float r;
  asm("v_exp_f32 %0, %1" : "=v"(r) : "v"(x));
  return r;
}

// async global -> LDS, 16 B per lane (wave writes base + lane*16)
__device__ __forceinline__ void gl16(const void* g, void* l) {
  __builtin_amdgcn_global_load_lds(
      (const __attribute__((address_space(1))) void*)g,
      (__attribute__((address_space(3))) void*)l, 16, 0, 0);
}

// ---------------- prep (fused): cast x to bf16 + all four weight transposes ----------------
__global__ __launch_bounds__(256) void k_prep(
    const float* __restrict__ x1, const float* __restrict__ x2,
    const float* __restrict__ Wqkv1, const float* __restrict__ Wqkv2,
    const float* __restrict__ Wp1, const float* __restrict__ Wp2,
    uint16_t* __restrict__ xb,
    uint16_t* __restrict__ wqkvt, uint16_t* __restrict__ wpt) {
  const int tid = threadIdx.x;
  if (blockIdx.x < 3072) {
    int i = blockIdx.x * 256 + tid;           // float4 index
    const int per = MROWS * DIMC / 4;         // 393216 per stream
    const float* src = (i < per) ? x1 : x2;
    int j = (i < per) ? i : (i - per);
    float4 v = reinterpret_cast<const float4*>(src)[j];
    reinterpret_cast<ushort4*>(xb)[i] =
        make_ushort4(f2bf(v.x), f2bf(v.y), f2bf(v.z), f2bf(v.w));
    return;
  }
  __shared__ uint16_t tile[32][33];
  int id = blockIdx.x - 3072;
  const float* src; uint16_t* dst; int C, xo, yo;
  if (id < 3456) {                 // 2 x (72*24) tiles for Wqkv
    int s = id / 1728; id %= 1728;
    src = s ? Wqkv2 : Wqkv1; dst = wqkvt + (size_t)s * NQKV * DIMC; C = NQKV;
    xo = id % 72; yo = id / 72;
  } else {                         // 2 x (24*24) tiles for Wp
    id -= 3456; int s = id / 576; id %= 576;
    src = s ? Wp2 : Wp1; dst = wpt + (size_t)s * DIMC * DIMC; C = DIMC;
    xo = id % 24; yo = id / 24;
  }
  const int R = DIMC;
  int c0 = xo * 32, r0 = yo * 32;
  int tx = tid & 31, ty = tid >> 5;
  for (int rr = ty; rr < 32; rr += 8)
    tile[rr][tx] = f2bf(src[(size_t)(r0 + rr) * C + c0 + tx]);
  __syncthreads();
  for (int rr = ty; rr < 32; rr += 8)
    dst[(size_t)(c0 + rr) * R + r0 + tx] = tile[tx][rr];
}

// ---------------- QKV GEMM v5: single bf16 pass, 128x64 tile, BK=64 ----------------
__global__ __launch_bounds__(256) void k_qkv_gemm(
    const uint16_t* __restrict__ xb,
    const uint16_t* __restrict__ wt,   // [2][2304][768] (W transposed)
    uint16_t* __restrict__ qo, uint16_t* __restrict__ ko, uint16_t* __restrict__ vto) {
  __shared__ __align__(16) uint16_t Ax[2][128][64];
  __shared__ __align__(16) uint16_t Bt[2][64][64];

  int flat = blockIdx.x + 16 * blockIdx.y + 576 * blockIdx.z;   // 1152 blocks
  flat = (flat & 7) * 144 + (flat >> 3);
  const int yb = flat % 36;
  const int xbk = (flat / 36) % 16;
  const int s  = flat / 576;
  const int m0 = xbk * 128;
  const int col0 = yb * 64;

  const uint16_t* x_s  = xb + (size_t)s * MROWS * DIMC;
  const uint16_t* wt_s = wt + (size_t)s * NQKV * DIMC;

  const int tid = threadIdx.x;
  const int w = tid >> 6, lane = tid & 63;
  const int lr = lane & 15, g = lane >> 4;
  const int srow8 = lane >> 3;                    // 0..7
  const int schunk8 = ((lane & 7) ^ srow8) * 8;   // pre-swizzled source chunk

  f32x4 acc[2][4] = {};

  size_t aoff[4], boff[2];
#pragma unroll
  for (int j = 0; j < 4; ++j)
    aoff[j] = (size_t)(m0 + w * 32 + j * 8 + srow8) * DIMC + schunk8;
#pragma unroll
  for (int j = 0; j < 2; ++j)
    boff[j] = (size_t)(col0 + w * 16 + j * 8 + srow8) * DIMC + schunk8;

#define STAGE(B, K0) do {                                  \
    gl16(x_s  + aoff[0] + (K0), &Ax[B][w * 32 +  0][0]);   \
    gl16(x_s  + aoff[1] + (K0), &Ax[B][w * 32 +  8][0]);   \
    gl16(x_s  + aoff[2] + (K0), &Ax[B][w * 32 + 16][0]);   \
    gl16(x_s  + aoff[3] + (K0), &Ax[B][w * 32 + 24][0]);   \
    gl16(wt_s + boff[0] + (K0), &Bt[B][w * 16 +  0][0]);   \
    gl16(wt_s + boff[1] + (K0), &Bt[B][w * 16 +  8][0]); } while (0)

  STAGE(0, 0);                       // 6 loads in flight

  for (int kt = 0; kt < 12; ++kt) {
    const int cur = kt & 1;
    if (kt < 11) {
      STAGE(cur ^ 1, (kt + 1) * 64);
      asm volatile("s_waitcnt vmcnt(6)" ::: "memory");
    } else {
      asm volatile("s_waitcnt vmcnt(0)" ::: "memory");
    }
    __builtin_amdgcn_s_barrier();
    __builtin_amdgcn_sched_barrier(0);

    bf16x8 ah[2][2], bb[4][2];
#pragma unroll
    for (int fm = 0; fm < 2; ++fm)
#pragma unroll
      for (int kk = 0; kk < 2; ++kk) {
        const int ch = ((kk * 4 + g) ^ (lr & 7)) * 8;
        ah[fm][kk] = *reinterpret_cast<const bf16x8*>(&Ax[cur][w * 32 + fm * 16 + lr][ch]);
      }
#pragma unroll
    for (int fn = 0; fn < 4; ++fn)
#pragma unroll
      for (int kk = 0; kk < 2; ++kk) {
        const int ch = ((kk * 4 + g) ^ (lr & 7)) * 8;
        bb[fn][kk] = *reinterpret_cast<const bf16x8*>(&Bt[cur][fn * 16 + lr][ch]);
      }

    asm volatile("s_waitcnt lgkmcnt(0)" ::: "memory");
    __builtin_amdgcn_sched_barrier(0);
    __builtin_amdgcn_s_setprio(1);
#pragma unroll
    for (int fm = 0; fm < 2; ++fm)
#pragma unroll
      for (int fn = 0; fn < 4; ++fn)
#pragma unroll
        for (int kk = 0; kk < 2; ++kk)
          acc[fm][fn] = __builtin_amdgcn_mfma_f32_16x16x32_bf16(ah[fm][kk], bb[fn][kk], acc[fm][fn], 0, 0, 0);
    __builtin_amdgcn_s_setprio(0);
    __builtin_amdgcn_sched_barrier(0);
    __builtin_amdgcn_s_barrier();
  }
#undef STAGE

  const int t = col0 / 768;
  const int cbase = col0 % 768;
  const int h = cbase >> 6;
  uint16_t* q_s  = qo  + (size_t)s * 1572864;
  uint16_t* k_s  = ko  + (size_t)s * 1572864;
  uint16_t* vt_s = vto + (size_t)s * 1572864;
#pragma unroll
  for (int fm = 0; fm < 2; ++fm)
#pragma unroll
    for (int fn = 0; fn < 4; ++fn) {
      const int dh = fn * 16 + lr;
#pragma unroll
      for (int i = 0; i < 4; ++i) {
        int m = m0 + w * 32 + fm * 16 + g * 4 + i;
        int b_ = m >> 10, n = m & 1023;
        float v = acc[fm][fn][i];
        if (t == 0)
          q_s[((size_t)(b_ * HEADS + h) * SEQ + n) * DH + dh] = f2bf(v * 0.125f);
        else if (t == 1)
          k_s[((size_t)(b_ * HEADS + h) * SEQ + n) * DH + dh] = f2bf(v);
        else
          vt_s[((size_t)(b_ * HEADS + h) * DH + dh) * SEQ + n] = f2bf(v);
      }
    }
}

// ---------------- fused dual-pass flash attention v6 (r11, frozen best) ----------------
#define SWKEY(r) ((((r) >> 2) ^ (r)) & 7)
#define MFMA16 __builtin_amdgcn_mfma_f32_16x16x32_bf16

__global__ __launch_bounds__(256) void k_attn(
    const uint16_t* __restrict__ q, const uint16_t* __restrict__ k,
    const uint16_t* __restrict__ vt, uint16_t* __restrict__ o) {
  __shared__ uint16_t Klds[2][64][64];   // [key][dh], chunk c holds global chunk c^SWKEY(row)
  __shared__ uint16_t Vlds[2][64][64];   // [dh][key], same swizzle

  int bid = blockIdx.x;
  bid = (bid & 7) * 96 + (bid >> 3);
  const int qt = bid & 15;
  int rest = bid >> 4;            // 0..47
  const int h = rest % 12;
  int rest2 = rest / 12;          // 0..3
  const int b = rest2 & 1;
  const int s = rest2 >> 1;

  const int tid = threadIdx.x;
  const int w = tid >> 6, lane = tid & 63;
  const int lr = lane & 15;
  const int g = lane >> 4;        // 0..3
  const int hi8 = g * 8;

  const uint16_t* q_s = q + (size_t)s * 1572864 +
                        ((size_t)(b * HEADS + h) * SEQ + qt * 64 + w * 16 + lr) * DH;
  const bf16x8 qf0 = *reinterpret_cast<const bf16x8*>(&q_s[hi8]);
  const bf16x8 qf1 = *reinterpret_cast<const bf16x8*>(&q_s[32 + hi8]);

  const int klo = (lr >> 2) * 8 + (lr & 3);

  const int r0 = tid >> 3;                    // 0..31 (and r0+32; same SWKEY)
  const int c0 = tid & 7;
  const int swck = 8 * (c0 ^ SWKEY(r0));

  const uint16_t* kbase0 = k  + (size_t)s * 1572864 + (size_t)(b * HEADS + h) * SEQ * DH;
  const uint16_t* vbase0 = vt + (size_t)s * 1572864 + (size_t)(b * HEADS + h) * DH * SEQ;
  const uint16_t* kbase1 = k  + (size_t)(1 - s) * 1572864 + (size_t)(b * HEADS + h) * SEQ * DH;
  const uint16_t* vbase1 = vt + (size_t)(1 - s) * 1572864 + (size_t)(b * HEADS + h) * DH * SEQ;

  u32x4 kr0, kr1, vr0, vr1;

#define LOADT(T) { const int tt = (T); const int kt_ = tt & 15;                             \
    const uint16_t* kp = (tt >= 16) ? kbase1 : kbase0;                                      \
    const uint16_t* vp = (tt >= 16) ? vbase1 : vbase0;                                      \
    kr0 = *reinterpret_cast<const u32x4*>(&kp[(size_t)(kt_ * 64 + r0) * DH + c0 * 8]);      \
    kr1 = *reinterpret_cast<const u32x4*>(&kp[(size_t)(kt_ * 64 + r0 + 32) * DH + c0 * 8]); \
    vr0 = *reinterpret_cast<const u32x4*>(&vp[(size_t)r0 * SEQ + kt_ * 64 + c0 * 8]);       \
    vr1 = *reinterpret_cast<const u32x4*>(&vp[(size_t)(r0 + 32) * SEQ + kt_ * 64 + c0 * 8]); }

#define STORET(B) {                                               \
    *reinterpret_cast<u32x4*>(&Klds[B][r0][swck]) = kr0;          \
    *reinterpret_cast<u32x4*>(&Klds[B][r0 + 32][swck]) = kr1;     \
    *reinterpret_cast<u32x4*>(&Vlds[B][r0][swck]) = vr0;          \
    *reinterpret_cast<u32x4*>(&Vlds[B][r0 + 32][swck]) = vr1; }

  LOADT(0);
  STORET(0);
  __syncthreads();

  f32x4 Oacc[4] = {};
  f32x4 Ofin[4] = {};
  float lrow = 0.f;

#define COMPUTE(CUR)                                                              \
  {                                                                               \
    f32x4 S[4];                                                                   \
    __builtin_amdgcn_s_setprio(1);                                                \
    _Pragma("unroll")                                                             \
    for (int fn = 0; fn < 4; ++fn) {                                              \
      const int krow = klo + 4 * (fn & 1) + 32 * (fn >> 1);                       \
      const int sw = SWKEY(krow);                                                 \
      bf16x8 ka = *reinterpret_cast<const bf16x8*>(&Klds[CUR][krow][8 * (g ^ sw)]);        \
      bf16x8 kb = *reinterpret_cast<const bf16x8*>(&Klds[CUR][krow][8 * ((4 + g) ^ sw)]);  \
      f32x4 z = {};                                                               \
      z = MFMA16(ka, qf0, z, 0, 0, 0);                                            \
      S[fn] = MFMA16(kb, qf1, z, 0, 0, 0);                                        \
    }                                                                             \
    __builtin_amdgcn_s_setprio(0);                                                \
    float rs0 = 0.f, rs1 = 0.f, rs2 = 0.f, rs3 = 0.f;                             \
    _Pragma("unroll")                                                             \
    for (int i = 0; i < 4; ++i) {                                                 \
      float p0 = fexp2(fmaf(S[0][i], 1.442695041f, -17.31234049f));               \
      float p1 = fexp2(fmaf(S[1][i], 1.442695041f, -17.31234049f));               \
      float p2 = fexp2(fmaf(S[2][i], 1.442695041f, -17.31234049f));               \
      float p3 = fexp2(fmaf(S[3][i], 1.442695041f, -17.31234049f));               \
      S[0][i] = p0; S[1][i] = p1; S[2][i] = p2; S[3][i] = p3;                     \
      rs0 += p0; rs1 += p1; rs2 += p2; rs3 += p3;                                 \
    }                                                                             \
    lrow += (rs0 + rs1) + (rs2 + rs3);                                            \
    bf16x8 pa0, pa1;                                                              \
    _Pragma("unroll")                                                             \
    for (int i = 0; i < 4; ++i) {                                                 \
      pa0[i] = (__bf16)S[0][i]; pa0[4 + i] = (__bf16)S[1][i];                     \
      pa1[i] = (__bf16)S[2][i]; pa1[4 + i] = (__bf16)S[3][i];                     \
    }                                                                             \
    __builtin_amdgcn_s_setprio(1);                                                \
    _Pragma("unroll")                                                             \
    for (int fn = 0; fn < 4; ++fn) {                                              \
      const int vrow = fn * 16 + lr;                                              \
      const int sw = SWKEY(vrow);                                                 \
      bf16x8 va = *reinterpret_cast<const bf16x8*>(&Vlds[CUR][vrow][8 * (g ^ sw)]);        \
      bf16x8 vb = *reinterpret_cast<const bf16x8*>(&Vlds[CUR][vrow][8 * ((4 + g) ^ sw)]);  \
      Oacc[fn] = MFMA16(pa0, va, Oacc[fn], 0, 0, 0);                              \
      Oacc[fn] = MFMA16(pa1, vb, Oacc[fn], 0, 0, 0);                              \
    }                                                                             \
    __builtin_amdgcn_s_setprio(0);                                                \
  }

#define PASS_EPI(RESET)                                                           \
  {                                                                               \
    float lsum = lrow + __shfl_xor(lrow, 16);                                     \
    lsum += __shfl_xor(lsum, 32);                                                 \
    const float linv = 1.f / lsum;                                                \
    float li0 = __shfl(linv, 20 * g + 0), li1 = __shfl(linv, 20 * g + 1);         \
    float li2 = __shfl(linv, 20 * g + 2), li3 = __shfl(linv, 20 * g + 3);         \
    _Pragma("unroll")                                                             \
    for (int fn = 0; fn < 4; ++fn) {                                              \
      Ofin[fn][0] += Oacc[fn][0] * li0; Ofin[fn][1] += Oacc[fn][1] * li1;         \
      Ofin[fn][2] += Oacc[fn][2] * li2; Ofin[fn][3] += Oacc[fn][3] * li3;         \
    }                                                                             \
    if (RESET) {                                                                  \
      lrow = 0.f;                                                                 \
      _Pragma("unroll") for (int fn = 0; fn < 4; ++fn) Oacc[fn] = f32x4{};        \
    }                                                                             \
  }

#pragma unroll 1
  for (int t2 = 0; t2 < 16; ++t2) {
    LOADT(2 * t2 + 1);
    COMPUTE(0);
    STORET(1);
    __syncthreads();
    if (t2 < 15) LOADT(2 * t2 + 2);
    COMPUTE(1);
    if (t2 == 7)  PASS_EPI(1);
    if (t2 == 15) PASS_EPI(0);
    if (t2 < 15) STORET(0);
    __syncthreads();
  }
#undef LOADT
#undef STORET
#undef COMPUTE
#undef PASS_EPI

  uint16_t* o_s = o + (size_t)s * MROWS * DIMC;
#pragma unroll
  for (int fn = 0; fn < 4; ++fn)
#pragma unroll
    for (int i = 0; i < 4; ++i) {
      int n = qt * 64 + w * 16 + g * 4 + i;
      int col = h * 64 + fn * 16 + lr;
      o_s[(size_t)(b * SEQ + n) * DIMC + col] = f2bf(Ofin[fn][i]);
    }
}

// ---------------- projection GEMM v4 (r11, frozen) ----------------
__global__ __launch_bounds__(256) void k_proj_gemm(
    const uint16_t* __restrict__ o, const uint16_t* __restrict__ wpt,
    const float* __restrict__ bp1, const float* __restrict__ bp2,
    float* __restrict__ out) {
  __shared__ __align__(16) uint16_t At[2][128][32];
  __shared__ __align__(16) uint16_t Bt[2][64][32];

  int flat = blockIdx.x + 16 * blockIdx.y + 192 * blockIdx.z;   // 384 blocks
  flat = (flat & 7) * 48 + (flat >> 3);
  const int yb = flat % 12;
  const int xb = (flat / 12) % 16;
  const int s  = flat / 192;
  const int m0 = xb * 128;
  const int col0 = yb * 64;

  const uint16_t* o_s = o + (size_t)s * MROWS * DIMC;
  const uint16_t* w_s = wpt + (size_t)s * DIMC * DIMC;
  const float* bias = (s == 0) ? bp1 : bp2;
  float* out_s = out + (size_t)s * MROWS * DIMC;

  const int tid = threadIdx.x;
  const int w = tid >> 6, lane = tid & 63;
  const int lr = lane & 15, g = lane >> 4;
  const int pc = (g ^ ((lr >> 1) & 3)) * 8;
  const int srow = lane >> 2;
  const int schunk = ((lane & 3) ^ ((lane >> 3) & 3)) * 8;

  f32x4 acc[2][4] = {};

  const size_t aoff0 = (size_t)(m0 + w * 32 + srow) * DIMC + schunk;
  const size_t aoff1 = (size_t)(m0 + w * 32 + 16 + srow) * DIMC + schunk;
  const size_t boff  = (size_t)(col0 + w * 16 + srow) * DIMC + schunk;

#define STAGE(B, K0) do {                                      \
    gl16(o_s + aoff0 + (K0), &At[B][w * 32][0]);               \
    gl16(o_s + aoff1 + (K0), &At[B][w * 32 + 16][0]);          \
    gl16(w_s + boff  + (K0), &Bt[B][w * 16][0]); } while (0)

  STAGE(0, 0);

  for (int kt = 0; kt < 24; ++kt) {
    const int cur = kt & 1;
    if (kt < 23) {
      STAGE(cur ^ 1, (kt + 1) * 32);
      asm volatile("s_waitcnt vmcnt(3)" ::: "memory");
    } else {
      asm volatile("s_waitcnt vmcnt(0)" ::: "memory");
    }
    __builtin_amdgcn_s_barrier();
    __builtin_amdgcn_sched_barrier(0);

    bf16x8 a[2], bb[4];
#pragma unroll
    for (int f = 0; f < 2; ++f)
      a[f] = *reinterpret_cast<const bf16x8*>(&At[cur][w * 32 + f * 16 + lr][pc]);
#pragma unroll
    for (int f = 0; f < 4; ++f)
      bb[f] = *reinterpret_cast<const bf16x8*>(&Bt[cur][f * 16 + lr][pc]);

    asm volatile("s_waitcnt lgkmcnt(0)" ::: "memory");
    __builtin_amdgcn_sched_barrier(0);
    __builtin_amdgcn_s_setprio(1);
#pragma unroll
    for (int fm = 0; fm < 2; ++fm)
#pragma unroll
      for (int fn = 0; fn < 4; ++fn)
        acc[fm][fn] = __builtin_amdgcn_mfma_f32_16x16x32_bf16(a[fm], bb[fn], acc[fm][fn], 0, 0, 0);
    __builtin_amdgcn_s_setprio(0);
    __builtin_amdgcn_sched_barrier(0);
    __builtin_amdgcn_s_barrier();
  }
#undef STAGE

#pragma unroll
  for (int fm = 0; fm < 2; ++fm)
#pragma unroll
    for (int fn = 0; fn < 4; ++fn) {
      const int col = col0 + fn * 16 + lr;
      const float bv = bias[col];
#pragma unroll
      for (int i = 0; i < 4; ++i) {
        int m = m0 + w * 32 + fm * 16 + g * 4 + i;
        out_s[(size_t)m * DIMC + col] = acc[fm][fn][i] + bv;
      }
    }
}

extern "C" void kernel_launch(void* const* d_in, const int* in_sizes, int n_in,
                              void* d_out, int out_size, void* d_ws, size_t ws_size,
                              hipStream_t stream) {
  const float* x1    = (const float*)d_in[0];
  const float* x2    = (const float*)d_in[1];
  const float* Wqkv1 = (const float*)d_in[2];
  const float* Wqkv2 = (const float*)d_in[3];
  const float* Wp1   = (const float*)d_in[4];
  const float* bp1   = (const float*)d_in[5];
  const float* Wp2   = (const float*)d_in[6];
  const float* bp2   = (const float*)d_in[7];
  float* out = (float*)d_out;

  uint8_t* ws = (uint8_t*)d_ws;
  uint16_t* xbuf  = (uint16_t*)(ws);             // 2*2048*768 bf16 = 6291456 B
  uint16_t* wqkvt = (uint16_t*)(ws + 12582912);  // 2*2304*768 = 7077888 B
  uint16_t* wpt   = (uint16_t*)(ws + 19660800);  // 2*768*768  = 2359296 B
  uint16_t* qb    = (uint16_t*)(ws + 22020096);  // 2*1572864  = 6291456 B
  uint16_t* kb    = (uint16_t*)(ws + 28311552);
  uint16_t* vtb   = (uint16_t*)(ws + 34603008);
  uint16_t* ob    = (uint16_t*)(ws + 40894464);  // total 47185920 B

  k_prep<<<7680, 256, 0, stream>>>(x1, x2, Wqkv1, Wqkv2, Wp1, Wp2, xbuf, wqkvt, wpt);
  k_qkv_gemm<<<dim3(16, 36, 2), 256, 0, stream>>>(xbuf, wqkvt, qb, kb, vtb);
  k_attn<<<768, 256, 0, stream>>>(qb, kb, vtb, ob);
  k_proj_gemm<<<dim3(16, 12, 2), 256, 0, stream>>>(ob, wpt, bp1, bp2, out);
}